// Round 1
// baseline (12272.299 us; speedup 1.0000x reference)
//
#include <hip/hip_runtime.h>
#include <hip/hip_bf16.h>

#define NH 8
#define NF 16
#define NIN 256
#define HF 128   // NH*NF

// ---------------- GEMM: feat = x @ W  [N,256]x[256,128] ----------------
#define BM 128
#define BN 128
#define BK 8
#define TM 8
#define TN 8

__global__ __launch_bounds__(256) void gemm_kernel(const float* __restrict__ A,
                                                   const float* __restrict__ B,
                                                   float* __restrict__ C, int M) {
    __shared__ float As[BK][BM];
    __shared__ float Bs[BK][BN];
    const int tid = threadIdx.x;
    const int block_row = blockIdx.x * BM;
    const int tx = tid & 15;          // -> N direction, TN=8 cols
    const int ty = tid >> 4;          // -> M direction, TM=8 rows
    const int a_row = tid >> 1;
    const int a_col = (tid & 1) * 4;
    const int b_row = tid >> 5;
    const int b_col = (tid & 31) * 4;

    float acc[TM][TN];
#pragma unroll
    for (int i = 0; i < TM; i++)
#pragma unroll
        for (int j = 0; j < TN; j++) acc[i][j] = 0.f;

    for (int k0 = 0; k0 < NIN; k0 += BK) {
        const int garow = block_row + a_row;
        float4 av = make_float4(0.f, 0.f, 0.f, 0.f);
        if (garow < M) av = *(const float4*)&A[(size_t)garow * NIN + k0 + a_col];
        As[a_col + 0][a_row] = av.x;
        As[a_col + 1][a_row] = av.y;
        As[a_col + 2][a_row] = av.z;
        As[a_col + 3][a_row] = av.w;
        float4 bv = *(const float4*)&B[(size_t)(k0 + b_row) * HF + b_col];
        *((float4*)&Bs[b_row][b_col]) = bv;
        __syncthreads();
#pragma unroll
        for (int kk = 0; kk < BK; kk++) {
            float ar[TM], br[TN];
            *(float4*)&ar[0] = *(const float4*)&As[kk][ty * TM];
            *(float4*)&ar[4] = *(const float4*)&As[kk][ty * TM + 4];
            *(float4*)&br[0] = *(const float4*)&Bs[kk][tx * TN];
            *(float4*)&br[4] = *(const float4*)&Bs[kk][tx * TN + 4];
#pragma unroll
            for (int i = 0; i < TM; i++)
#pragma unroll
                for (int j = 0; j < TN; j++)
                    acc[i][j] = fmaf(ar[i], br[j], acc[i][j]);
        }
        __syncthreads();
    }
#pragma unroll
    for (int i = 0; i < TM; i++) {
        const int row = block_row + ty * TM + i;
        if (row < M) {
            *(float4*)&C[(size_t)row * HF + tx * TN] =
                make_float4(acc[i][0], acc[i][1], acc[i][2], acc[i][3]);
            *(float4*)&C[(size_t)row * HF + tx * TN + 4] =
                make_float4(acc[i][4], acc[i][5], acc[i][6], acc[i][7]);
        }
    }
}

// ---------------- el/er: per (n,h) dot of feat row with attn vectors ----------------
__global__ __launch_bounds__(256) void el_er_kernel(const float* __restrict__ feat,
                                                    const float* __restrict__ attn_l,
                                                    const float* __restrict__ attn_r,
                                                    float* __restrict__ el,
                                                    float* __restrict__ er, int NH_total) {
    const int idx = blockIdx.x * blockDim.x + threadIdx.x;
    if (idx >= NH_total) return;
    const int h = idx & (NH - 1);
    const float* f = &feat[(size_t)idx * NF];
    const float* al = &attn_l[h * NF];
    const float* ar = &attn_r[h * NF];
    float sl = 0.f, sr = 0.f;
#pragma unroll
    for (int j = 0; j < NF; j++) {
        const float v = f[j];
        sl = fmaf(v, al[j], sl);
        sr = fmaf(v, ar[j], sr);
    }
    el[idx] = sl;
    er[idx] = sr;
}

// ---------------- edge pass 1: s[dst,h] += exp(leaky(el[src,h]+er[dst,h])) ----------------
__global__ __launch_bounds__(256) void edge_sum_kernel(const int* __restrict__ src,
                                                       const int* __restrict__ dst,
                                                       const float* __restrict__ el,
                                                       const float* __restrict__ er,
                                                       float* __restrict__ s, int E) {
    const int e = blockIdx.x * blockDim.x + threadIdx.x;
    if (e >= E) return;
    const int si = src[e];
    const int di = dst[e];
    float l[NH], r[NH];
    *(float4*)&l[0] = *(const float4*)&el[(size_t)si * NH];
    *(float4*)&l[4] = *(const float4*)&el[(size_t)si * NH + 4];
    *(float4*)&r[0] = *(const float4*)&er[(size_t)di * NH];
    *(float4*)&r[4] = *(const float4*)&er[(size_t)di * NH + 4];
#pragma unroll
    for (int h = 0; h < NH; h++) {
        float v = l[h] + r[h];
        v = v > 0.f ? v : 0.2f * v;
        atomicAdd(&s[(size_t)di * NH + h], expf(v));
    }
}

// ---------------- edge pass 2: rst[dst,h,:] += a * feat[src,h,:] ----------------
__global__ __launch_bounds__(256) void edge_agg_kernel(const int* __restrict__ src,
                                                       const int* __restrict__ dst,
                                                       const float* __restrict__ el,
                                                       const float* __restrict__ er,
                                                       const float* __restrict__ s,
                                                       const float* __restrict__ feat,
                                                       float* __restrict__ rst, long long EH) {
    const long long idx = (long long)blockIdx.x * blockDim.x + threadIdx.x;
    if (idx >= EH) return;
    const int e = (int)(idx >> 3);
    const int h = (int)(idx & 7);
    const int si = src[e];
    const int di = dst[e];
    float v = el[(size_t)si * NH + h] + er[(size_t)di * NH + h];
    v = v > 0.f ? v : 0.2f * v;
    const float a = expf(v) / fmaxf(s[(size_t)di * NH + h], 1e-9f);
    const float4* f4 = (const float4*)&feat[((size_t)si * NH + h) * NF];
    float* o = &rst[((size_t)di * NH + h) * NF];
#pragma unroll
    for (int j = 0; j < 4; j++) {
        const float4 fv = f4[j];
        atomicAdd(&o[j * 4 + 0], a * fv.x);
        atomicAdd(&o[j * 4 + 1], a * fv.y);
        atomicAdd(&o[j * 4 + 2], a * fv.z);
        atomicAdd(&o[j * 4 + 3], a * fv.w);
    }
}

// ---------------- finalize: out[n,f] = mean_h(rst[n,h,f] + bias[h,f]) ----------------
__global__ __launch_bounds__(256) void finalize_kernel(const float* __restrict__ rst,
                                                       const float* __restrict__ bias,
                                                       float* __restrict__ out, int NFtot) {
    const int idx = blockIdx.x * blockDim.x + threadIdx.x;
    if (idx >= NFtot) return;
    const int n = idx >> 4;
    const int f = idx & 15;
    float acc = 0.f;
#pragma unroll
    for (int h = 0; h < NH; h++)
        acc += rst[(size_t)n * HF + h * NF + f] + bias[h * NF + f];
    out[idx] = acc * 0.125f;
}

extern "C" void kernel_launch(void* const* d_in, const int* in_sizes, int n_in,
                              void* d_out, int out_size, void* d_ws, size_t ws_size,
                              hipStream_t stream) {
    const float* x      = (const float*)d_in[0];
    const float* W      = (const float*)d_in[1];
    const float* attn_l = (const float*)d_in[2];
    const float* attn_r = (const float*)d_in[3];
    const float* bias   = (const float*)d_in[4];
    const int*   src    = (const int*)d_in[5];
    const int*   dst    = (const int*)d_in[6];
    float* out = (float*)d_out;

    const int N = in_sizes[0] / NIN;
    const int E = in_sizes[5];

    // workspace carve-up (all fp32):
    float* feat = (float*)d_ws;                  // N*HF
    float* el   = feat + (size_t)N * HF;         // N*NH
    float* er   = el + (size_t)N * NH;           // N*NH
    float* s    = er + (size_t)N * NH;           // N*NH
    float* rst  = s + (size_t)N * NH;            // N*HF   (contiguous after s)

    // zero s and rst in one contiguous memset
    hipMemsetAsync(s, 0, ((size_t)N * NH + (size_t)N * HF) * sizeof(float), stream);

    gemm_kernel<<<(N + BM - 1) / BM, 256, 0, stream>>>(x, W, feat, N);
    el_er_kernel<<<(N * NH + 255) / 256, 256, 0, stream>>>(feat, attn_l, attn_r, el, er, N * NH);
    edge_sum_kernel<<<(E + 255) / 256, 256, 0, stream>>>(src, dst, el, er, s, E);
    const long long EH = (long long)E * NH;
    edge_agg_kernel<<<(int)((EH + 255) / 256), 256, 0, stream>>>(src, dst, el, er, s, feat, rst, EH);
    finalize_kernel<<<(N * NF + 255) / 256, 256, 0, stream>>>(rst, bias, out, N * NF);
}

// Round 2
// 502.058 us; speedup vs baseline: 24.4440x; 24.4440x over previous
//
#include <hip/hip_runtime.h>
#include <hip/hip_bf16.h>

#define NH 8
#define NF 16
#define NIN 256
#define HF 128   // NH*NF

// ---------------- GEMM: feat = x @ W  [N,256]x[256,128] ----------------
#define BM 128
#define BN 128
#define BK 8
#define TM 8
#define TN 8

__global__ __launch_bounds__(256) void gemm_kernel(const float* __restrict__ A,
                                                   const float* __restrict__ B,
                                                   float* __restrict__ C, int M) {
    __shared__ float As[BK][BM];
    __shared__ float Bs[BK][BN];
    const int tid = threadIdx.x;
    const int block_row = blockIdx.x * BM;
    const int tx = tid & 15;          // -> N direction, TN=8 cols
    const int ty = tid >> 4;          // -> M direction, TM=8 rows
    const int a_row = tid >> 1;
    const int a_col = (tid & 1) * 4;
    const int b_row = tid >> 5;
    const int b_col = (tid & 31) * 4;

    float acc[TM][TN];
#pragma unroll
    for (int i = 0; i < TM; i++)
#pragma unroll
        for (int j = 0; j < TN; j++) acc[i][j] = 0.f;

    for (int k0 = 0; k0 < NIN; k0 += BK) {
        const int garow = block_row + a_row;
        float4 av = make_float4(0.f, 0.f, 0.f, 0.f);
        if (garow < M) av = *(const float4*)&A[(size_t)garow * NIN + k0 + a_col];
        As[a_col + 0][a_row] = av.x;
        As[a_col + 1][a_row] = av.y;
        As[a_col + 2][a_row] = av.z;
        As[a_col + 3][a_row] = av.w;
        float4 bv = *(const float4*)&B[(size_t)(k0 + b_row) * HF + b_col];
        *((float4*)&Bs[b_row][b_col]) = bv;
        __syncthreads();
#pragma unroll
        for (int kk = 0; kk < BK; kk++) {
            float ar[TM], br[TN];
            *(float4*)&ar[0] = *(const float4*)&As[kk][ty * TM];
            *(float4*)&ar[4] = *(const float4*)&As[kk][ty * TM + 4];
            *(float4*)&br[0] = *(const float4*)&Bs[kk][tx * TN];
            *(float4*)&br[4] = *(const float4*)&Bs[kk][tx * TN + 4];
#pragma unroll
            for (int i = 0; i < TM; i++)
#pragma unroll
                for (int j = 0; j < TN; j++)
                    acc[i][j] = fmaf(ar[i], br[j], acc[i][j]);
        }
        __syncthreads();
    }
#pragma unroll
    for (int i = 0; i < TM; i++) {
        const int row = block_row + ty * TM + i;
        if (row < M) {
            *(float4*)&C[(size_t)row * HF + tx * TN] =
                make_float4(acc[i][0], acc[i][1], acc[i][2], acc[i][3]);
            *(float4*)&C[(size_t)row * HF + tx * TN + 4] =
                make_float4(acc[i][4], acc[i][5], acc[i][6], acc[i][7]);
        }
    }
}

// ---------------- el/er: per (n,h) dot of feat row with attn vectors ----------------
__global__ __launch_bounds__(256) void el_er_kernel(const float* __restrict__ feat,
                                                    const float* __restrict__ attn_l,
                                                    const float* __restrict__ attn_r,
                                                    float* __restrict__ el,
                                                    float* __restrict__ er, int NH_total) {
    const int idx = blockIdx.x * blockDim.x + threadIdx.x;
    if (idx >= NH_total) return;
    const int h = idx & (NH - 1);
    const float* f = &feat[(size_t)idx * NF];
    const float* al = &attn_l[h * NF];
    const float* ar = &attn_r[h * NF];
    float sl = 0.f, sr = 0.f;
#pragma unroll
    for (int j = 0; j < NF; j++) {
        const float v = f[j];
        sl = fmaf(v, al[j], sl);
        sr = fmaf(v, ar[j], sr);
    }
    el[idx] = sl;
    er[idx] = sr;
}

// ---------------- CSR build step 1: count in-degree ----------------
__global__ __launch_bounds__(256) void count_kernel(const int* __restrict__ dst,
                                                    int* __restrict__ deg, int E) {
    const int e = blockIdx.x * blockDim.x + threadIdx.x;
    if (e >= E) return;
    atomicAdd(&deg[dst[e]], 1);
}

// ---------------- CSR build step 2: exclusive scan (single block, 1024 thr) ----------------
__global__ __launch_bounds__(1024) void scan_kernel(const int* __restrict__ deg,
                                                    int* __restrict__ rowptr,
                                                    int* __restrict__ cursor, int N) {
    __shared__ int wsum[16];
    __shared__ int sbase;
    const int tid = threadIdx.x;
    const int lane = tid & 63;
    const int wave = tid >> 6;
    if (tid == 0) sbase = 0;
    __syncthreads();
    for (int start = 0; start < N; start += 1024) {
        const int i = start + tid;
        const int v = (i < N) ? deg[i] : 0;
        int incl = v;
#pragma unroll
        for (int off = 1; off < 64; off <<= 1) {
            int t = __shfl_up(incl, off, 64);
            if (lane >= off) incl += t;
        }
        if (lane == 63) wsum[wave] = incl;
        __syncthreads();
        int wbase = 0, total = 0;
#pragma unroll
        for (int w = 0; w < 16; w++) {
            const int ws = wsum[w];
            if (w < wave) wbase += ws;
            total += ws;
        }
        const int excl = sbase + wbase + incl - v;
        if (i < N) { rowptr[i] = excl; cursor[i] = excl; }
        __syncthreads();
        if (tid == 0) sbase += total;
        __syncthreads();
    }
    if (tid == 0) rowptr[N] = sbase;
}

// ---------------- CSR build step 3: scatter src ids sorted by dst ----------------
__global__ __launch_bounds__(256) void scatter_kernel(const int* __restrict__ src,
                                                      const int* __restrict__ dst,
                                                      int* __restrict__ cursor,
                                                      int* __restrict__ srcs, int E) {
    const int e = blockIdx.x * blockDim.x + threadIdx.x;
    if (e >= E) return;
    const int pos = atomicAdd(&cursor[dst[e]], 1);
    srcs[pos] = src[e];
}

// ---------------- fused aggregation: softmax + weighted sum + bias + head-mean ----------------
// one 128-thread block per destination node; no atomics, output written once
__global__ __launch_bounds__(128) void agg_kernel(const int* __restrict__ rowptr,
                                                  const int* __restrict__ srcs,
                                                  const float* __restrict__ el,
                                                  const float* __restrict__ er,
                                                  const float* __restrict__ feat,
                                                  const float* __restrict__ bias,
                                                  float* __restrict__ out) {
    const int n = blockIdx.x;
    const int tid = threadIdx.x;
    __shared__ float lds_score[16][NH];
    __shared__ int   lds_src[16];
    __shared__ float lds_er[NH];
    __shared__ float lds_s[NH];
    __shared__ float lds_val[HF];

    const int begin = rowptr[n];
    const int end   = rowptr[n + 1];
    if (tid < NH) lds_er[tid] = er[(size_t)n * NH + tid];
    __syncthreads();

    const int eA = tid >> 3, hA = tid & 7;    // phase A: (edge_in_chunk, head)
    const int hB = tid >> 4, fB = tid & 15;   // phase B: (head, feat)

    float acc = 0.f;
    float psum = 0.f;
    for (int base = begin; base < end; base += 16) {
        const int cn = min(16, end - base);
        if (eA < cn) {
            const int si = srcs[base + eA];
            if (hA == 0) lds_src[eA] = si;
            float v = el[(size_t)si * NH + hA] + lds_er[hA];
            v = v > 0.f ? v : 0.2f * v;
            const float sc = expf(v);
            lds_score[eA][hA] = sc;
            psum += sc;
        }
        __syncthreads();
        for (int j = 0; j < cn; j++) {
            acc = fmaf(lds_score[j][hB],
                       feat[(size_t)lds_src[j] * HF + hB * NF + fB], acc);
        }
        __syncthreads();
    }

    // reduce psum over the 16 eA-threads per head
    lds_val[tid] = psum;
    __syncthreads();
    if (tid < NH) {
        float s = 0.f;
#pragma unroll
        for (int k = 0; k < 16; k++) s += lds_val[k * NH + tid];
        lds_s[tid] = fmaxf(s, 1e-9f);
    }
    __syncthreads();

    const float val = acc / lds_s[hB] + bias[hB * NF + fB];
    lds_val[hB * NF + fB] = val;
    __syncthreads();
    if (tid < NF) {
        float o = 0.f;
#pragma unroll
        for (int h = 0; h < NH; h++) o += lds_val[h * NF + tid];
        out[(size_t)n * NF + tid] = o * 0.125f;
    }
}

extern "C" void kernel_launch(void* const* d_in, const int* in_sizes, int n_in,
                              void* d_out, int out_size, void* d_ws, size_t ws_size,
                              hipStream_t stream) {
    const float* x      = (const float*)d_in[0];
    const float* W      = (const float*)d_in[1];
    const float* attn_l = (const float*)d_in[2];
    const float* attn_r = (const float*)d_in[3];
    const float* bias   = (const float*)d_in[4];
    const int*   src    = (const int*)d_in[5];
    const int*   dst    = (const int*)d_in[6];
    float* out = (float*)d_out;

    const int N = in_sizes[0] / NIN;
    const int E = in_sizes[5];

    // workspace carve-up:
    float* feat   = (float*)d_ws;                    // N*HF fp32
    float* el     = feat + (size_t)N * HF;           // N*NH
    float* er     = el + (size_t)N * NH;             // N*NH
    int*   deg    = (int*)(er + (size_t)N * NH);     // N
    int*   rowptr = deg + N;                         // N+1
    int*   cursor = rowptr + N + 1;                  // N
    int*   srcs   = cursor + N;                      // E

    hipMemsetAsync(deg, 0, (size_t)N * sizeof(int), stream);

    gemm_kernel<<<(N + BM - 1) / BM, 256, 0, stream>>>(x, W, feat, N);
    el_er_kernel<<<(N * NH + 255) / 256, 256, 0, stream>>>(feat, attn_l, attn_r, el, er, N * NH);
    count_kernel<<<(E + 255) / 256, 256, 0, stream>>>(dst, deg, E);
    scan_kernel<<<1, 1024, 0, stream>>>(deg, rowptr, cursor, N);
    scatter_kernel<<<(E + 255) / 256, 256, 0, stream>>>(src, dst, cursor, srcs, E);
    agg_kernel<<<N, 128, 0, stream>>>(rowptr, srcs, el, er, feat, bias, out);
}

// Round 3
// 376.139 us; speedup vs baseline: 32.6270x; 1.3348x over previous
//
#include <hip/hip_runtime.h>
#include <hip/hip_bf16.h>

#define NH 8
#define NF 16
#define NIN 256
#define HF 128   // NH*NF

typedef __attribute__((ext_vector_type(8))) short bf16x8;
typedef __attribute__((ext_vector_type(4))) float f32x4;

__device__ __forceinline__ unsigned short f2bf(float f) {
    union { float f; unsigned int u; } v; v.f = f;
    unsigned int r = v.u + 0x7FFFu + ((v.u >> 16) & 1u);
    return (unsigned short)(r >> 16);
}
__device__ __forceinline__ float bf2f(unsigned short b) {
    union { unsigned int u; float f; } v; v.u = ((unsigned int)b) << 16;
    return v.f;
}

// ---------------- MFMA GEMM: featb = bf16( x @ W ), split-bf16 for accuracy -------
// block = 256 thr (4 waves). Wave w owns n-tiles {2w, 2w+1} (cols 32w..32w+31),
// with W fragments register-resident for all 8 K-steps. A staged via LDS in
// 32-row chunks as hi/lo bf16 (pad +8 bf16 -> only 2-way LDS conflicts, free).
#define GROWS 128
__global__ __launch_bounds__(256) void gemm_mfma(const float* __restrict__ A,
                                                 const float* __restrict__ W,
                                                 unsigned short* __restrict__ featb, int M) {
    __shared__ unsigned short AsH[32][264];
    __shared__ unsigned short AsL[32][264];
    const int tid = threadIdx.x;
    const int wave = tid >> 6, lane = tid & 63;
    const int quad = lane >> 4, lq = lane & 15;
    const int row0 = blockIdx.x * GROWS;

    // B fragments: B[k][n], n = lq, k = quad*8 + j  (16x16x32 layout)
    bf16x8 bfrag[8][2];
#pragma unroll
    for (int h2 = 0; h2 < 2; h2++) {
        const int col = (wave * 2 + h2) * 16 + lq;
#pragma unroll
        for (int kk = 0; kk < 8; kk++) {
            const int kb = kk * 32 + quad * 8;
            bf16x8 f;
#pragma unroll
            for (int j = 0; j < 8; j++)
                f[j] = (short)f2bf(W[(size_t)(kb + j) * HF + col]);
            bfrag[kk][h2] = f;
        }
    }

    const int srow = tid >> 3;  // staging row 0..31

    for (int c = 0; c < 4; c++) {
        const int crow0 = row0 + c * 32;
        __syncthreads();
#pragma unroll
        for (int i = 0; i < 8; i++) {
            const int col = ((tid & 7) + i * 8) * 4;
            const int gr = crow0 + srow;
            float4 v = make_float4(0.f, 0.f, 0.f, 0.f);
            if (gr < M) v = *(const float4*)&A[(size_t)gr * NIN + col];
            const unsigned short h0 = f2bf(v.x), h1 = f2bf(v.y),
                                 h2b = f2bf(v.z), h3 = f2bf(v.w);
            *(ushort4*)&AsH[srow][col] = make_ushort4(h0, h1, h2b, h3);
            *(ushort4*)&AsL[srow][col] =
                make_ushort4(f2bf(v.x - bf2f(h0)), f2bf(v.y - bf2f(h1)),
                             f2bf(v.z - bf2f(h2b)), f2bf(v.w - bf2f(h3)));
        }
        __syncthreads();
#pragma unroll
        for (int s = 0; s < 2; s++) {
            f32x4 acc0 = {0.f, 0.f, 0.f, 0.f};
            f32x4 acc1 = {0.f, 0.f, 0.f, 0.f};
            const int ar = s * 16 + lq;
#pragma unroll
            for (int kk = 0; kk < 8; kk++) {
                const bf16x8 ah = *(const bf16x8*)&AsH[ar][kk * 32 + quad * 8];
                const bf16x8 al = *(const bf16x8*)&AsL[ar][kk * 32 + quad * 8];
                acc0 = __builtin_amdgcn_mfma_f32_16x16x32_bf16(ah, bfrag[kk][0], acc0, 0, 0, 0);
                acc1 = __builtin_amdgcn_mfma_f32_16x16x32_bf16(ah, bfrag[kk][1], acc1, 0, 0, 0);
                acc0 = __builtin_amdgcn_mfma_f32_16x16x32_bf16(al, bfrag[kk][0], acc0, 0, 0, 0);
                acc1 = __builtin_amdgcn_mfma_f32_16x16x32_bf16(al, bfrag[kk][1], acc1, 0, 0, 0);
            }
            // C layout: col = lq, row = quad*4 + r
#pragma unroll
            for (int r = 0; r < 4; r++) {
                const int gr = crow0 + s * 16 + quad * 4 + r;
                if (gr < M) {
                    featb[(size_t)gr * HF + (wave * 2 + 0) * 16 + lq] = f2bf(acc0[r]);
                    featb[(size_t)gr * HF + (wave * 2 + 1) * 16 + lq] = f2bf(acc1[r]);
                }
            }
        }
    }
}

// ---------------- el/er from bf16 feat ----------------
__global__ __launch_bounds__(256) void el_er_kernel(const unsigned short* __restrict__ featb,
                                                    const float* __restrict__ attn_l,
                                                    const float* __restrict__ attn_r,
                                                    float* __restrict__ el,
                                                    float* __restrict__ er, int NH_total) {
    const int idx = blockIdx.x * blockDim.x + threadIdx.x;
    if (idx >= NH_total) return;
    const int h = idx & (NH - 1);
    const unsigned short* f = &featb[(size_t)idx * NF];
    const float* al = &attn_l[h * NF];
    const float* ar = &attn_r[h * NF];
    float sl = 0.f, sr = 0.f;
#pragma unroll
    for (int j = 0; j < NF; j++) {
        const float v = bf2f(f[j]);
        sl = fmaf(v, al[j], sl);
        sr = fmaf(v, ar[j], sr);
    }
    el[idx] = sl;
    er[idx] = sr;
}

// ---------------- CSR: count in-degree ----------------
__global__ __launch_bounds__(256) void count_kernel(const int* __restrict__ dst,
                                                    int* __restrict__ deg, int E) {
    const int e = blockIdx.x * blockDim.x + threadIdx.x;
    if (e >= E) return;
    atomicAdd(&deg[dst[e]], 1);
}

// ---------------- CSR: exclusive scan (single block, 1024 thr) ----------------
__global__ __launch_bounds__(1024) void scan_kernel(const int* __restrict__ deg,
                                                    int* __restrict__ rowptr, int N) {
    __shared__ int wsum[16];
    __shared__ int sbase;
    const int tid = threadIdx.x;
    const int lane = tid & 63;
    const int wave = tid >> 6;
    if (tid == 0) sbase = 0;
    __syncthreads();
    for (int start = 0; start < N; start += 1024) {
        const int i = start + tid;
        const int v = (i < N) ? deg[i] : 0;
        int incl = v;
#pragma unroll
        for (int off = 1; off < 64; off <<= 1) {
            int t = __shfl_up(incl, off, 64);
            if (lane >= off) incl += t;
        }
        if (lane == 63) wsum[wave] = incl;
        __syncthreads();
        int wbase = 0, total = 0;
#pragma unroll
        for (int w = 0; w < 16; w++) {
            const int ws = wsum[w];
            if (w < wave) wbase += ws;
            total += ws;
        }
        const int excl = sbase + wbase + incl - v;
        if (i < N) rowptr[i] = excl;
        __syncthreads();
        if (tid == 0) sbase += total;
        __syncthreads();
    }
    if (tid == 0) rowptr[N] = sbase;
}

// ---------------- bucket cursor init: bcursor[b] = rowptr[64b] ----------------
__global__ __launch_bounds__(256) void initb_kernel(const int* __restrict__ rowptr,
                                                    int* __restrict__ bcursor, int NB) {
    const int b = blockIdx.x * blockDim.x + threadIdx.x;
    if (b < NB) bcursor[b] = rowptr[b << 6];
}

// ---------------- stage 1: bin edges into 64-node buckets ----------------
// packed entry: src (16 bits) | dst_local (6 bits) << 16
#define BCH 4096
__global__ __launch_bounds__(256) void bin_kernel(const int* __restrict__ src,
                                                  const int* __restrict__ dst,
                                                  int* __restrict__ bcursor,
                                                  unsigned int* __restrict__ binned,
                                                  int E, int NB) {
    __shared__ unsigned int hist[800];
    __shared__ unsigned short lpos[BCH];
    const int tid = threadIdx.x;
    const int base = blockIdx.x * BCH;
    for (int b = tid; b < NB; b += 256) hist[b] = 0;
    __syncthreads();
    const int cnt = min(BCH, E - base);
    for (int i = tid; i < cnt; i += 256) {
        const int b = dst[base + i] >> 6;
        lpos[i] = (unsigned short)atomicAdd(&hist[b], 1u);
    }
    __syncthreads();
    for (int b = tid; b < NB; b += 256) {
        const unsigned int c = hist[b];
        if (c) hist[b] = (unsigned int)atomicAdd(&bcursor[b], (int)c);
    }
    __syncthreads();
    for (int i = tid; i < cnt; i += 256) {
        const int d = dst[base + i];
        const int b = d >> 6;
        const unsigned int pos = hist[b] + (unsigned int)lpos[i];
        binned[pos] = (unsigned int)src[base + i] | ((unsigned int)(d & 63) << 16);
    }
}

// ---------------- stage 2: exact CSR within each bucket (LDS cursors) ----------------
__global__ __launch_bounds__(256) void csr_kernel(const int* __restrict__ rowptr,
                                                  const unsigned int* __restrict__ binned,
                                                  int* __restrict__ srcs, int N) {
    __shared__ int cur[64];
    const int b = blockIdx.x;
    const int node0 = b << 6;
    const int tid = threadIdx.x;
    const int hi = min(node0 + 64, N);
    const int begin = rowptr[node0];
    const int end = rowptr[hi];
    if (tid < 64) cur[tid] = (node0 + tid < N) ? rowptr[node0 + tid] : 0;
    __syncthreads();
    for (int i = begin + tid; i < end; i += 256) {
        const unsigned int p = binned[i];
        const int pos = atomicAdd(&cur[p >> 16], 1);
        srcs[pos] = (int)(p & 0xFFFFu);
    }
}

// ---------------- fused aggregation: softmax + weighted sum + bias + head-mean ----
__global__ __launch_bounds__(128) void agg_kernel(const int* __restrict__ rowptr,
                                                  const int* __restrict__ srcs,
                                                  const float* __restrict__ el,
                                                  const float* __restrict__ er,
                                                  const unsigned short* __restrict__ featb,
                                                  const float* __restrict__ bias,
                                                  float* __restrict__ out) {
    const int n = blockIdx.x;
    const int tid = threadIdx.x;
    __shared__ float lds_score[16][NH];
    __shared__ int   lds_src[16];
    __shared__ float lds_er[NH];
    __shared__ float lds_s[NH];
    __shared__ float lds_val[HF];

    const int begin = rowptr[n];
    const int end   = rowptr[n + 1];
    if (tid < NH) lds_er[tid] = er[(size_t)n * NH + tid];
    __syncthreads();

    const int eA = tid >> 3, hA = tid & 7;    // phase A: (edge_in_chunk, head)
    const int hB = tid >> 4, fB = tid & 15;   // phase B: (head, feat)

    float acc = 0.f;
    float psum = 0.f;
    for (int base = begin; base < end; base += 16) {
        const int cn = min(16, end - base);
        if (eA < cn) {
            const int si = srcs[base + eA];
            if (hA == 0) lds_src[eA] = si;
            float v = el[(size_t)si * NH + hA] + lds_er[hA];
            v = v > 0.f ? v : 0.2f * v;
            const float sc = expf(v);
            lds_score[eA][hA] = sc;
            psum += sc;
        }
        __syncthreads();
        for (int j = 0; j < cn; j++) {
            acc = fmaf(lds_score[j][hB],
                       bf2f(featb[(size_t)lds_src[j] * HF + hB * NF + fB]), acc);
        }
        __syncthreads();
    }

    lds_val[tid] = psum;
    __syncthreads();
    if (tid < NH) {
        float s = 0.f;
#pragma unroll
        for (int k = 0; k < 16; k++) s += lds_val[k * NH + tid];
        lds_s[tid] = fmaxf(s, 1e-9f);
    }
    __syncthreads();

    const float val = acc / lds_s[hB] + bias[hB * NF + fB];
    lds_val[hB * NF + fB] = val;
    __syncthreads();
    if (tid < NF) {
        float o = 0.f;
#pragma unroll
        for (int h = 0; h < NH; h++) o += lds_val[h * NF + tid];
        out[(size_t)n * NF + tid] = o * 0.125f;
    }
}

extern "C" void kernel_launch(void* const* d_in, const int* in_sizes, int n_in,
                              void* d_out, int out_size, void* d_ws, size_t ws_size,
                              hipStream_t stream) {
    const float* x      = (const float*)d_in[0];
    const float* W      = (const float*)d_in[1];
    const float* attn_l = (const float*)d_in[2];
    const float* attn_r = (const float*)d_in[3];
    const float* bias   = (const float*)d_in[4];
    const int*   src    = (const int*)d_in[5];
    const int*   dst    = (const int*)d_in[6];
    float* out = (float*)d_out;

    const int N = in_sizes[0] / NIN;
    const int E = in_sizes[5];
    const int NB = (N + 63) >> 6;

    // workspace carve-up
    char* w = (char*)d_ws;
    unsigned short* featb = (unsigned short*)w; w += (size_t)N * HF * 2;
    float* el     = (float*)w; w += (size_t)N * NH * 4;
    float* er     = (float*)w; w += (size_t)N * NH * 4;
    int* deg      = (int*)w;   w += (size_t)N * 4;
    int* rowptr   = (int*)w;   w += (size_t)(N + 16) * 4;
    int* bcursor  = (int*)w;   w += (size_t)((NB + 15) & ~15) * 4;
    unsigned int* binned = (unsigned int*)w; w += (size_t)E * 4;
    int* srcs     = (int*)w;

    hipMemsetAsync(deg, 0, (size_t)N * sizeof(int), stream);

    gemm_mfma<<<(N + GROWS - 1) / GROWS, 256, 0, stream>>>(x, W, featb, N);
    el_er_kernel<<<(N * NH + 255) / 256, 256, 0, stream>>>(featb, attn_l, attn_r, el, er, N * NH);
    count_kernel<<<(E + 255) / 256, 256, 0, stream>>>(dst, deg, E);
    scan_kernel<<<1, 1024, 0, stream>>>(deg, rowptr, N);
    initb_kernel<<<(NB + 255) / 256, 256, 0, stream>>>(rowptr, bcursor, NB);
    bin_kernel<<<(E + BCH - 1) / BCH, 256, 0, stream>>>(src, dst, bcursor, binned, E, NB);
    csr_kernel<<<NB, 256, 0, stream>>>(rowptr, binned, srcs, N);
    agg_kernel<<<N, 128, 0, stream>>>(rowptr, srcs, el, er, featb, bias, out);
}